// Round 13
// baseline (295.447 us; speedup 1.0000x reference)
//
#include <hip/hip_runtime.h>
#include <hip/hip_bf16.h>
#include <math.h>

typedef __attribute__((ext_vector_type(4))) float  f32x4;
typedef __attribute__((ext_vector_type(8))) __bf16 bf16x8;
typedef __attribute__((ext_vector_type(4))) unsigned int u32x4;

__device__ __forceinline__ f32x4 MF(bf16x8 a, bf16x8 b, f32x4 c) {
    return __builtin_amdgcn_mfma_f32_16x16x32_bf16(a, b, c, 0, 0, 0);
}

__device__ __forceinline__ f32x4 zero4() { f32x4 z = {0.f, 0.f, 0.f, 0.f}; return z; }

// packed f32->bf16 (RNE), 2 elems/instr
__device__ __forceinline__ unsigned int pkbf(float lo, float hi) {
    unsigned int r;
    asm("v_cvt_pk_bf16_f32 %0, %1, %2" : "=v"(r) : "v"(lo), "v"(hi));
    return r;
}
__device__ __forceinline__ unsigned long long pk4(f32x4 x) {
    return (unsigned long long)pkbf(x[0], x[1]) | ((unsigned long long)pkbf(x[2], x[3]) << 32);
}

// B-fragment (BT row-major, contiguous K): lane holds BT[row][k0..k0+7], f32 -> bf16
__device__ __forceinline__ bf16x8 bfrag_g(const float* W, int ldk, int row, int k0) {
    const float* p = W + (size_t)row * ldk + k0;
    bf16x8 r;
#pragma unroll
    for (int e = 0; e < 8; ++e) r[e] = (__bf16)p[e];
    return r;
}

// ---- LDS layout (bytes), M=16 atoms/tile, 2-slot pipeline ----
#define RAW(b)   ((b) * 12288)          // raw V tiles (bf16), ping-pong
#define VPR      24576                  // v' = v1*ss tile (single bank)
#define HB(b)    (36864 + (b) * 8192)   // L0 MLP1 input [s | norm], ping-pong
#define HP(b)    (53248 + (b) * 8192)   // L1 MLP1 input [gate | norm'], ping-pong
#define S1_OFF   69632                  // L0 MLP1 output (16x128 bf16)
#define RED_OFF  73728                  // 8 waves * 16 f32
#define LDS_BYTES 74240

// A-fragment read from swizzled LDS tile
__device__ __forceinline__ bf16x8 afrag(const unsigned char* base, int rb, int row, int kb) {
    u32x4 q = *(const u32x4*)(base + row * rb + (kb ^ ((row & 7) << 4)));
    return __builtin_bit_cast(bf16x8, q);
}

__global__ __launch_bounds__(512, 2) void eqsc_main(
    const float* __restrict__ S, const float* __restrict__ V,
    const float* __restrict__ u0w, const float* __restrict__ v0w,
    const float* __restrict__ a0w1, const float* __restrict__ a0b1,
    const float* __restrict__ a0w2, const float* __restrict__ a0b2,
    const float* __restrict__ u1w, const float* __restrict__ v1w,
    const float* __restrict__ a1w1, const float* __restrict__ a1b1,
    const float* __restrict__ a1w2, const float* __restrict__ a1b2,
    const float* __restrict__ outw, const float* __restrict__ outbp,
    float* __restrict__ sOut, int NT)
{
    __shared__ __align__(16) unsigned char lds[LDS_BYTES];
    const int tid  = threadIdx.x;
    const int lane = tid & 63;
    const int wv   = tid >> 6;
    const int l15  = lane & 15;
    const int lg   = lane >> 4;
    const int grow = wv * 16 + l15;   // weight-fragment row (output feature)
    const int kbb  = lg << 4;         // k-byte base within a 64B kt chunk
    const int fb0  = wv * 16 + (lg << 2);   // epilogue: this lane's 4-feature base
    const int erow = l15;                    // epilogue: this lane's atom row
    const int eswz = (erow & 7) << 4;

    // ---- folded readout (vector): wfv[e] = sum_g a1w2[g,fb0+e]*outw[g] ----
    f32x4 wfv = zero4();
    float cf = 0.f;
    for (int g = 0; g < 128; ++g) {
        float og = outw[g];
        f32x4 w4 = *(const f32x4*)(a1w2 + g * 128 + fb0);
#pragma unroll
        for (int e = 0; e < 4; ++e) wfv[e] += w4[e] * og;
        cf += a1b2[g] * og;
    }
    cf += outbp[0];

    // ---- persistent weight fragments (bf16): 144 regs ----
    bf16x8 uw0f[4], vw0f[4], w2g0[4], w2s0[4], vw1f[4];
    bf16x8 w1f0[8], w1f1[8];
#pragma unroll
    for (int kt = 0; kt < 4; ++kt) {
        int k0 = kt * 32 + lg * 8;
        uw0f[kt] = bfrag_g(u0w, 128, grow, k0);
        vw0f[kt] = bfrag_g(v0w, 128, grow, k0);
        w2g0[kt] = bfrag_g(a0w2, 128, grow, k0);
        w2s0[kt] = bfrag_g(a0w2, 128, 128 + grow, k0);
        vw1f[kt] = bfrag_g(v1w, 128, grow, k0);
    }
#pragma unroll
    for (int kt = 0; kt < 8; ++kt) {
        int k0 = kt * 32 + lg * 8;
        w1f0[kt] = bfrag_g(a0w1, 256, grow, k0);
        w1f1[kt] = bfrag_g(a1w1, 256, grow, k0);
    }
    const f32x4 b1_0v = *(const f32x4*)(a0b1 + fb0);
    const f32x4 b2g0v = *(const f32x4*)(a0b2 + fb0);
    const f32x4 b2s0v = *(const f32x4*)(a0b2 + 128 + fb0);
    const f32x4 b1_1v = *(const f32x4*)(a1b1 + fb0);

    const int stride = gridDim.x;
    const int t0 = blockIdx.x;
    const int NI = (NT > t0) ? ((NT - t0 + stride - 1) / stride) : 0;

    // ---- prologue: stage tile t0 into raw[0] + H[0] s-half ----
    if (NI > 0) {
        f32x4 vld[3], sld;
#pragma unroll
        for (int j = 0; j < 3; ++j) {
            int c = tid + (j << 9);
            int d = c >> 9, rem = c & 511;
            int row = rem >> 5, c4 = rem & 31;
            vld[j] = *(const f32x4*)(V + (((size_t)((t0 << 4) + row) * 3 + d) << 7) + (c4 << 2));
        }
        { int row = tid >> 5, c4 = tid & 31;
          sld = *(const f32x4*)(S + (((size_t)((t0 << 4) + row)) << 7) + (c4 << 2)); }
#pragma unroll
        for (int j = 0; j < 3; ++j) {
            int c = tid + (j << 9);
            int d = c >> 9, rem = c & 511;
            int row = rem >> 5, c4 = rem & 31;
            *(unsigned long long*)(lds + RAW(0) + (d << 12) + row * 256 +
                                   ((c4 << 3) ^ ((row & 7) << 4))) = pk4(vld[j]);
        }
        { int row = tid >> 5, c4 = tid & 31;
          *(unsigned long long*)(lds + HB(0) + row * 512 +
                                 ((c4 << 3) ^ ((row & 7) << 4))) = pk4(sld); }
    }
    __syncthreads();

    for (int i = 0; i < NI + 3; ++i) {
        const bool yv  = (i < NI);                       // tile Y = i
        const bool xv  = (i >= 1) && (i - 1 < NI);       // tile X = i-1
        const bool wvd = (i >= 2) && (i - 2 < NI);       // tile W = i-2 (P5)
        const bool fvd = (i >= 3) && (i - 3 < NI);       // tile F = i-3 (flush)
        const int  ty  = t0 + i * stride;
        const int  tz  = ty + stride;
        const bool zv  = (i + 1 < NI);
        const int  rY  = i & 1;
        const int  rX  = (i + 1) & 1;   // == (i-1)&1

        // ================= slot A =================
        // issue Z loads ; flush sOut(F) ; P1-Y (v2-GEMM+norm) ; P3-X (sg/ss + u-GEMM -> gate, v')
        f32x4 vld[3], sld;
        if (zv) {
#pragma unroll
            for (int j = 0; j < 3; ++j) {
                int c = tid + (j << 9);
                int d = c >> 9, rem = c & 511;
                int row = rem >> 5, c4 = rem & 31;
                vld[j] = *(const f32x4*)(V + (((size_t)((tz << 4) + row) * 3 + d) << 7) + (c4 << 2));
            }
            { int row = tid >> 5, c4 = tid & 31;
              sld = *(const f32x4*)(S + (((size_t)((tz << 4) + row)) << 7) + (c4 << 2)); }
        }
        if (fvd && tid < 16) {          // RED written at slot B of iter i-1 (tile i-3)
            float s = 0.f;
#pragma unroll
            for (int w = 0; w < 8; ++w) s += *((float*)(lds + RED_OFF) + (w << 4) + tid);
            sOut[((t0 + (i - 3) * stride) << 4) + tid] = s + cf;
        }
        if (yv) {                      // P1: v2 = V@v0w^T (swapped C), norm over d
            f32x4 n2 = zero4();
#pragma unroll
            for (int d = 0; d < 3; ++d) {
                f32x4 a2 = zero4();
#pragma unroll
                for (int kt = 0; kt < 4; ++kt)
                    a2 = MF(vw0f[kt], afrag(lds + RAW(rY) + (d << 12), 256, l15, (kt << 6) + kbb), a2);
#pragma unroll
                for (int e = 0; e < 4; ++e) { float x = a2[e] + 1e-8f; n2[e] += x * x; }
            }
            f32x4 nr;
#pragma unroll
            for (int e = 0; e < 4; ++e) nr[e] = sqrtf(n2[e]);
            *(unsigned long long*)(lds + HB(rY) + erow * 512 +
                ((256 + (fb0 << 1)) ^ eswz)) = pk4(nr);
        }
        if (xv) {                      // P3: sg|ss from S1 ; deferred u-GEMM from raw(X)
            f32x4 sg = zero4(), ssa = zero4();
#pragma unroll
            for (int kt = 0; kt < 4; ++kt) {
                bf16x8 a = afrag(lds + S1_OFF, 256, l15, (kt << 6) + kbb);
                sg  = MF(w2g0[kt], a, sg);
                ssa = MF(w2s0[kt], a, ssa);
            }
            f32x4 g, ssv;
#pragma unroll
            for (int e = 0; e < 4; ++e) {
                g[e]   = sg[e] + b2g0v[e];
                ssv[e] = ssa[e] + b2s0v[e];
            }
            *(unsigned long long*)(lds + HP(rX) + erow * 512 + ((fb0 << 1) ^ eswz)) = pk4(g);
#pragma unroll
            for (int d = 0; d < 3; ++d) {
                f32x4 u = zero4();
#pragma unroll
                for (int kt = 0; kt < 4; ++kt)
                    u = MF(uw0f[kt], afrag(lds + RAW(rX) + (d << 12), 256, l15, (kt << 6) + kbb), u);
                f32x4 vp;
#pragma unroll
                for (int e = 0; e < 4; ++e) vp[e] = u[e] * ssv[e];
                *(unsigned long long*)(lds + VPR + (d << 12) + erow * 256 +
                    ((fb0 << 1) ^ eswz)) = pk4(vp);
            }
        }
        __syncthreads();

        // ================= slot B =================
        // P2-Y (L0 MLP1) ; P4-X (L1 v-GEMM+norm') ; P5-W (L1 MLP1 + readout) ; write Z
        if (yv) {
            f32x4 m = zero4();
#pragma unroll
            for (int kt = 0; kt < 8; ++kt)
                m = MF(w1f0[kt], afrag(lds + HB(rY), 512, l15, (kt << 6) + kbb), m);
            f32x4 y;
#pragma unroll
            for (int e = 0; e < 4; ++e) {
                float x = m[e] + b1_0v[e];
                y[e] = x / (1.f + __expf(-x));
            }
            *(unsigned long long*)(lds + S1_OFF + erow * 256 + ((fb0 << 1) ^ eswz)) = pk4(y);
        }
        if (xv) {
            f32x4 n2 = zero4();
#pragma unroll
            for (int d = 0; d < 3; ++d) {
                f32x4 acc = zero4();
#pragma unroll
                for (int kt = 0; kt < 4; ++kt)
                    acc = MF(vw1f[kt], afrag(lds + VPR + (d << 12), 256, l15, (kt << 6) + kbb), acc);
#pragma unroll
                for (int e = 0; e < 4; ++e) { float x = acc[e] + 1e-8f; n2[e] += x * x; }
            }
            f32x4 nr;
#pragma unroll
            for (int e = 0; e < 4; ++e) nr[e] = sqrtf(n2[e]);
            *(unsigned long long*)(lds + HP(rX) + erow * 512 +
                ((256 + (fb0 << 1)) ^ eswz)) = pk4(nr);
        }
        if (wvd) {                     // P5 on W = i-2 ; HP bank (i-2+1)&1 == rY
            f32x4 m = zero4();
#pragma unroll
            for (int kt = 0; kt < 8; ++kt)
                m = MF(w1f1[kt], afrag(lds + HP(rY), 512, l15, (kt << 6) + kbb), m);
            float p = 0.f;
#pragma unroll
            for (int e = 0; e < 4; ++e) {
                float x = m[e] + b1_1v[e];
                p += (x / (1.f + __expf(-x))) * wfv[e];   // folded readout, f32
            }
            p += __shfl_xor(p, 16);
            p += __shfl_xor(p, 32);
            if (lane < 16)
                *((float*)(lds + RED_OFF) + (wv << 4) + lane) = p;
        }
        if (zv) {
#pragma unroll
            for (int j = 0; j < 3; ++j) {
                int c = tid + (j << 9);
                int d = c >> 9, rem = c & 511;
                int row = rem >> 5, c4 = rem & 31;
                *(unsigned long long*)(lds + RAW(rX) + (d << 12) + row * 256 +
                                       ((c4 << 3) ^ ((row & 7) << 4))) = pk4(vld[j]);
            }
            { int row = tid >> 5, c4 = tid & 31;
              *(unsigned long long*)(lds + HB(rX) + row * 512 +
                                     ((c4 << 3) ^ ((row & 7) << 4))) = pk4(sld); }
        }
        __syncthreads();
    }
}

// Dense masked pooling: y[b] = sum_a batch[b,a] * s_out[a]
__global__ __launch_bounds__(256) void eqsc_pool(const float* __restrict__ batch,
                                                 const float* __restrict__ s,
                                                 float* __restrict__ out,
                                                 int NA, int B, int CH)
{
    int b  = blockIdx.x % B;
    int ch = blockIdx.x / B;
    int a0 = ch * CH;
    int a1 = min(a0 + CH, NA);
    const float* br = batch + (size_t)b * NA;
    float acc = 0.f;
    for (int a = a0 + (threadIdx.x << 2); a < a1; a += 256 * 4) {
        f32x4 bb = *(const f32x4*)(br + a);
        f32x4 sv = *(const f32x4*)(s + a);
        acc += bb[0] * sv[0] + bb[1] * sv[1] + bb[2] * sv[2] + bb[3] * sv[3];
    }
#pragma unroll
    for (int off = 32; off > 0; off >>= 1) acc += __shfl_down(acc, off);
    __shared__ float wsum[4];
    if ((threadIdx.x & 63) == 0) wsum[threadIdx.x >> 6] = acc;
    __syncthreads();
    if (threadIdx.x == 0) atomicAdd(&out[b], wsum[0] + wsum[1] + wsum[2] + wsum[3]);
}

extern "C" void kernel_launch(void* const* d_in, const int* in_sizes, int n_in,
                              void* d_out, int out_size, void* d_ws, size_t ws_size,
                              hipStream_t stream)
{
    const float* S     = (const float*)d_in[0];
    const float* V     = (const float*)d_in[1];
    // d_in[2] = pos, unused by the reference
    const float* batch = (const float*)d_in[3];
    const float* u0w   = (const float*)d_in[4];
    const float* v0w   = (const float*)d_in[5];
    const float* a0w1  = (const float*)d_in[6];
    const float* a0b1  = (const float*)d_in[7];
    const float* a0w2  = (const float*)d_in[8];
    const float* a0b2  = (const float*)d_in[9];
    const float* u1w   = (const float*)d_in[10];
    const float* v1w   = (const float*)d_in[11];
    const float* a1w1  = (const float*)d_in[12];
    const float* a1b1  = (const float*)d_in[13];
    const float* a1w2  = (const float*)d_in[14];
    const float* a1b2  = (const float*)d_in[15];
    const float* outw  = (const float*)d_in[16];
    const float* outb  = (const float*)d_in[17];

    const int NA = in_sizes[0] / 128;
    const int NT = NA / 16;                  // 16 atoms per tile
    const int B  = in_sizes[3] / NA;
    float* sAtom = (float*)d_ws;

    hipMemsetAsync(d_out, 0, (size_t)out_size * sizeof(float), stream);

    eqsc_main<<<256, 512, 0, stream>>>(S, V, u0w, v0w, a0w1, a0b1, a0w2, a0b2,
                                       u1w, v1w, a1w1, a1b1, a1w2, a1b2,
                                       outw, outb, sAtom, NT);

    const int CH  = 16384;
    const int NCH = (NA + CH - 1) / CH;
    eqsc_pool<<<B * NCH, 256, 0, stream>>>(batch, sAtom, (float*)d_out, NA, B, CH);
}

// Round 14
// 245.066 us; speedup vs baseline: 1.2056x; 1.2056x over previous
//
#include <hip/hip_runtime.h>
#include <hip/hip_bf16.h>
#include <math.h>

typedef __attribute__((ext_vector_type(4))) float  f32x4;
typedef __attribute__((ext_vector_type(8))) __bf16 bf16x8;
typedef __attribute__((ext_vector_type(4))) unsigned int u32x4;

__device__ __forceinline__ f32x4 MF(bf16x8 a, bf16x8 b, f32x4 c) {
    return __builtin_amdgcn_mfma_f32_16x16x32_bf16(a, b, c, 0, 0, 0);
}

__device__ __forceinline__ f32x4 zero4() { f32x4 z = {0.f, 0.f, 0.f, 0.f}; return z; }

// packed f32->bf16 (RNE), 2 elems/instr
__device__ __forceinline__ unsigned int pkbf(float lo, float hi) {
    unsigned int r;
    asm("v_cvt_pk_bf16_f32 %0, %1, %2" : "=v"(r) : "v"(lo), "v"(hi));
    return r;
}
__device__ __forceinline__ unsigned long long pk4(f32x4 x) {
    return (unsigned long long)pkbf(x[0], x[1]) | ((unsigned long long)pkbf(x[2], x[3]) << 32);
}

// B-fragment (BT row-major, contiguous K): lane holds BT[row][k0..k0+7], f32 -> bf16
__device__ __forceinline__ bf16x8 bfrag_g(const float* W, int ldk, int row, int k0) {
    const float* p = W + (size_t)row * ldk + k0;
    bf16x8 r;
#pragma unroll
    for (int e = 0; e < 8; ++e) r[e] = (__bf16)p[e];
    return r;
}

// ---- LDS layout (bytes): padded rows + additive rotate swizzle ----
// VIN row 384B (K=128 + 112 rotate + pad), H row 640B (K=256), S1 row 384B.
// Rotation: physical = logical_kbyte + (row&7)*16  (per-row constant shift ->
// addresses are base + compile-time immediates; granule spread (4kt+lg+row&7)%8).
#define VSET     18432                  // 3 * 16 * 384
#define SET_SZ   28672                  // VSET + 16*640
#define RAW(b)   ((b) * SET_SZ)
#define HB(b)    ((b) * SET_SZ + VSET)
#define S1_OFF   57344                  // 16*384
#define RED_OFF  63488                  // 8 waves * 16 f32
#define LDS_BYTES 64000

// 16B LDS read at precomputed lane pointer + compile-time byte immediate
__device__ __forceinline__ bf16x8 ld16(const unsigned char* p, int imm) {
    return __builtin_bit_cast(bf16x8, *(const u32x4*)(p + imm));
}

__global__ __launch_bounds__(512, 2) void eqsc_main(
    const float* __restrict__ S, const float* __restrict__ V,
    const float* __restrict__ u0w, const float* __restrict__ v0w,
    const float* __restrict__ a0w1, const float* __restrict__ a0b1,
    const float* __restrict__ a0w2, const float* __restrict__ a0b2,
    const float* __restrict__ u1w, const float* __restrict__ v1w,
    const float* __restrict__ a1w1, const float* __restrict__ a1b1,
    const float* __restrict__ a1w2, const float* __restrict__ a1b2,
    const float* __restrict__ outw, const float* __restrict__ outbp,
    float* __restrict__ sOut, int NT)
{
    __shared__ __align__(16) unsigned char lds[LDS_BYTES];
    const int tid  = threadIdx.x;
    const int lane = tid & 63;
    const int wv   = tid >> 6;
    const int l15  = lane & 15;
    const int lg   = lane >> 4;
    const int grow = wv * 16 + l15;   // weight-fragment row (output feature)
    const int fb0  = wv * 16 + (lg << 2);   // epilogue: this lane's 4-feature base

    // lane-invariant address pieces (computed once)
    const int lgsw    = (lg + (l15 & 7)) << 4;             // read col base + rotate
    const int lrow384 = l15 * 384 + lgsw;                  // A-frag lane base, RB=384
    const int lrow640 = l15 * 640 + lgsw;                  // A-frag lane base, RB=640
    const int erot    = (fb0 << 1) + ((l15 & 7) << 4);     // epilogue store rotate
    const int eoffV   = l15 * 384 + erot;                  // v'/S1-style row store
    const int eoffH   = l15 * 640 + erot;                  // H row store (gate at +0, norm +256)

    // staging store offsets (iteration-invariant)
    int vstoff[3], sstoff;
#pragma unroll
    for (int j = 0; j < 3; ++j) {
        int c = tid + (j << 9);
        int d = c >> 9, rem = c & 511;
        int row = rem >> 5, c4 = rem & 31;
        vstoff[j] = d * 6144 + row * 384 + (c4 << 3) + ((row & 7) << 4);
    }
    { int row = tid >> 5, c4 = tid & 31;
      sstoff = row * 640 + (c4 << 3) + ((row & 7) << 4); }

    // ---- folded readout (vector): wfv[e] = sum_g a1w2[g,fb0+e]*outw[g] ----
    f32x4 wfv = zero4();
    float cf = 0.f;
    for (int g = 0; g < 128; ++g) {
        float og = outw[g];
        f32x4 w4 = *(const f32x4*)(a1w2 + g * 128 + fb0);
#pragma unroll
        for (int e = 0; e < 4; ++e) wfv[e] += w4[e] * og;
        cf += a1b2[g] * og;
    }
    cf += outbp[0];

    // ---- persistent weight fragments (bf16): 144 regs ----
    bf16x8 uw0f[4], vw0f[4], w2g0[4], w2s0[4], vw1f[4];
    bf16x8 w1f0[8], w1f1[8];
#pragma unroll
    for (int kt = 0; kt < 4; ++kt) {
        int k0 = kt * 32 + lg * 8;
        uw0f[kt] = bfrag_g(u0w, 128, grow, k0);
        vw0f[kt] = bfrag_g(v0w, 128, grow, k0);
        w2g0[kt] = bfrag_g(a0w2, 128, grow, k0);
        w2s0[kt] = bfrag_g(a0w2, 128, 128 + grow, k0);
        vw1f[kt] = bfrag_g(v1w, 128, grow, k0);
    }
#pragma unroll
    for (int kt = 0; kt < 8; ++kt) {
        int k0 = kt * 32 + lg * 8;
        w1f0[kt] = bfrag_g(a0w1, 256, grow, k0);
        w1f1[kt] = bfrag_g(a1w1, 256, grow, k0);
    }
    const f32x4 b1_0v = *(const f32x4*)(a0b1 + fb0);
    const f32x4 b2g0v = *(const f32x4*)(a0b2 + fb0);
    const f32x4 b2s0v = *(const f32x4*)(a0b2 + 128 + fb0);
    const f32x4 b1_1v = *(const f32x4*)(a1b1 + fb0);

    const int stride = gridDim.x;
    const int t0 = blockIdx.x;

    // ---- prologue: stage tile t0 into set 0 ----
    if (t0 < NT) {
        f32x4 vld[3], sld;
#pragma unroll
        for (int j = 0; j < 3; ++j) {
            int c = tid + (j << 9);
            int d = c >> 9, rem = c & 511;
            int row = rem >> 5, c4 = rem & 31;
            vld[j] = *(const f32x4*)(V + (((size_t)((t0 << 4) + row) * 3 + d) << 7) + (c4 << 2));
        }
        { int row = tid >> 5, c4 = tid & 31;
          sld = *(const f32x4*)(S + (((size_t)((t0 << 4) + row)) << 7) + (c4 << 2)); }
#pragma unroll
        for (int j = 0; j < 3; ++j)
            *(unsigned long long*)(lds + RAW(0) + vstoff[j]) = pk4(vld[j]);
        *(unsigned long long*)(lds + HB(0) + sstoff) = pk4(sld);
    }
    __syncthreads();

    int i = 0;
    for (int ty = t0; ty < NT + stride; ty += stride, ++i) {
        const bool yv = (ty < NT);
        const bool xv = (i > 0);
        const int  tz = ty + stride;
        const bool zv = (tz < NT);
        unsigned char* baseY = lds + (i & 1) * SET_SZ;
        unsigned char* baseX = lds + ((i & 1) ^ 1) * SET_SZ;
        const unsigned char* pVY = baseY + lrow384;          // RAW(Y) A-frags
        const unsigned char* pHY = baseY + VSET + lrow640;   // H(Y) A-frags
        const unsigned char* pVX = baseX + lrow384;
        const unsigned char* pHX = baseX + VSET + lrow640;
        const unsigned char* pS1 = lds + S1_OFF + lrow384;

        // ======== slot 1: Y.P1 (L0 u+v GEMMs) || X.P4 (L1 v-GEMM) ; issue Z loads ========
        f32x4 vld[3], sld;
        if (zv) {
#pragma unroll
            for (int j = 0; j < 3; ++j) {
                int c = tid + (j << 9);
                int d = c >> 9, rem = c & 511;
                int row = rem >> 5, c4 = rem & 31;
                vld[j] = *(const f32x4*)(V + (((size_t)((tz << 4) + row) * 3 + d) << 7) + (c4 << 2));
            }
            { int row = tid >> 5, c4 = tid & 31;
              sld = *(const f32x4*)(S + (((size_t)((tz << 4) + row)) << 7) + (c4 << 2)); }
        }

        f32x4 v1a[3];
        if (yv) {
            f32x4 n2 = zero4();
#pragma unroll
            for (int d = 0; d < 3; ++d) {
                f32x4 a1 = zero4(), a2 = zero4();
#pragma unroll
                for (int kt = 0; kt < 4; ++kt) {
                    bf16x8 a = ld16(pVY, d * 6144 + kt * 64);
                    a1 = MF(uw0f[kt], a, a1);   // swapped: C = (col=atom, row=feature)
                    a2 = MF(vw0f[kt], a, a2);
                }
                v1a[d] = a1;
#pragma unroll
                for (int e = 0; e < 4; ++e) { float x = a2[e] + 1e-8f; n2[e] += x * x; }
            }
            f32x4 nr;
#pragma unroll
            for (int e = 0; e < 4; ++e) nr[e] = sqrtf(n2[e]);
            *(unsigned long long*)(baseY + VSET + eoffH + 256) = pk4(nr);
        }
        if (xv) {
            f32x4 n2 = zero4();
#pragma unroll
            for (int d = 0; d < 3; ++d) {
                f32x4 acc = zero4();
#pragma unroll
                for (int kt = 0; kt < 4; ++kt)
                    acc = MF(vw1f[kt], ld16(pVX, d * 6144 + kt * 64), acc);
#pragma unroll
                for (int e = 0; e < 4; ++e) { float x = acc[e] + 1e-8f; n2[e] += x * x; }
            }
            f32x4 nr;
#pragma unroll
            for (int e = 0; e < 4; ++e) nr[e] = sqrtf(n2[e]);
            *(unsigned long long*)(baseX + VSET + eoffH + 256) = pk4(nr);
        }
        __syncthreads();

        // ======== slot 2: Y.P2 (L0 MLP1) || X.P5 (L1 MLP1 + folded readout) ; write V(Z) ========
        if (yv) {
            f32x4 m = zero4();
#pragma unroll
            for (int kt = 0; kt < 8; ++kt)
                m = MF(w1f0[kt], ld16(pHY, kt * 64), m);
            f32x4 y;
#pragma unroll
            for (int e = 0; e < 4; ++e) {
                float x = m[e] + b1_0v[e];
                y[e] = x / (1.f + __expf(-x));
            }
            *(unsigned long long*)(lds + S1_OFF + eoffV) = pk4(y);
        }
        if (xv) {
            f32x4 m = zero4();
#pragma unroll
            for (int kt = 0; kt < 8; ++kt)
                m = MF(w1f1[kt], ld16(pHX, kt * 64), m);
            float p = 0.f;
#pragma unroll
            for (int e = 0; e < 4; ++e) {
                float x = m[e] + b1_1v[e];
                p += (x / (1.f + __expf(-x))) * wfv[e];   // folded readout, f32
            }
            p += __shfl_xor(p, 16);
            p += __shfl_xor(p, 32);
            if (lane < 16)
                *((float*)(lds + RED_OFF) + (wv << 4) + lane) = p;
        }
        if (zv) {
#pragma unroll
            for (int j = 0; j < 3; ++j)
                *(unsigned long long*)(baseX + vstoff[j]) = pk4(vld[j]);
        }
        __syncthreads();

        // ======== slot 3: Y.P3 (L0 MLP2 + v'=v1*ss) ; write S(Z) ; sOut(X) ========
        if (yv) {
            f32x4 sg = zero4(), ssa = zero4();
#pragma unroll
            for (int kt = 0; kt < 4; ++kt) {
                bf16x8 a = ld16(pS1, kt * 64);
                sg  = MF(w2g0[kt], a, sg);
                ssa = MF(w2s0[kt], a, ssa);
            }
            f32x4 g, ssv;
#pragma unroll
            for (int e = 0; e < 4; ++e) {
                g[e]   = sg[e] + b2g0v[e];
                ssv[e] = ssa[e] + b2s0v[e];
            }
            *(unsigned long long*)(baseY + VSET + eoffH) = pk4(g);
#pragma unroll
            for (int d = 0; d < 3; ++d) {
                f32x4 vp;
#pragma unroll
                for (int e = 0; e < 4; ++e) vp[e] = v1a[d][e] * ssv[e];
                *(unsigned long long*)(baseY + d * 6144 + eoffV) = pk4(vp);
            }
        }
        if (zv)
            *(unsigned long long*)(baseX + VSET + sstoff) = pk4(sld);
        if (xv && tid < 16) {
            float s = 0.f;
#pragma unroll
            for (int w = 0; w < 8; ++w) s += *((float*)(lds + RED_OFF) + (w << 4) + tid);
            sOut[((ty - stride) << 4) + tid] = s + cf;
        }
        __syncthreads();
    }
}

// Dense masked pooling: y[b] = sum_a batch[b,a] * s_out[a]
__global__ __launch_bounds__(256) void eqsc_pool(const float* __restrict__ batch,
                                                 const float* __restrict__ s,
                                                 float* __restrict__ out,
                                                 int NA, int B, int CH)
{
    int b  = blockIdx.x % B;
    int ch = blockIdx.x / B;
    int a0 = ch * CH;
    int a1 = min(a0 + CH, NA);
    const float* br = batch + (size_t)b * NA;
    float acc = 0.f;
    for (int a = a0 + (threadIdx.x << 2); a < a1; a += 256 * 4) {
        f32x4 bb = *(const f32x4*)(br + a);
        f32x4 sv = *(const f32x4*)(s + a);
        acc += bb[0] * sv[0] + bb[1] * sv[1] + bb[2] * sv[2] + bb[3] * sv[3];
    }
#pragma unroll
    for (int off = 32; off > 0; off >>= 1) acc += __shfl_down(acc, off);
    __shared__ float wsum[4];
    if ((threadIdx.x & 63) == 0) wsum[threadIdx.x >> 6] = acc;
    __syncthreads();
    if (threadIdx.x == 0) atomicAdd(&out[b], wsum[0] + wsum[1] + wsum[2] + wsum[3]);
}

extern "C" void kernel_launch(void* const* d_in, const int* in_sizes, int n_in,
                              void* d_out, int out_size, void* d_ws, size_t ws_size,
                              hipStream_t stream)
{
    const float* S     = (const float*)d_in[0];
    const float* V     = (const float*)d_in[1];
    // d_in[2] = pos, unused by the reference
    const float* batch = (const float*)d_in[3];
    const float* u0w   = (const float*)d_in[4];
    const float* v0w   = (const float*)d_in[5];
    const float* a0w1  = (const float*)d_in[6];
    const float* a0b1  = (const float*)d_in[7];
    const float* a0w2  = (const float*)d_in[8];
    const float* a0b2  = (const float*)d_in[9];
    const float* u1w   = (const float*)d_in[10];
    const float* v1w   = (const float*)d_in[11];
    const float* a1w1  = (const float*)d_in[12];
    const float* a1b1  = (const float*)d_in[13];
    const float* a1w2  = (const float*)d_in[14];
    const float* a1b2  = (const float*)d_in[15];
    const float* outw  = (const float*)d_in[16];
    const float* outb  = (const float*)d_in[17];

    const int NA = in_sizes[0] / 128;
    const int NT = NA / 16;                  // 16 atoms per tile
    const int B  = in_sizes[3] / NA;
    float* sAtom = (float*)d_ws;

    hipMemsetAsync(d_out, 0, (size_t)out_size * sizeof(float), stream);

    eqsc_main<<<256, 512, 0, stream>>>(S, V, u0w, v0w, a0w1, a0b1, a0w2, a0b2,
                                       u1w, v1w, a1w1, a1b1, a1w2, a1b2,
                                       outw, outb, sAtom, NT);

    const int CH  = 16384;
    const int NCH = (NA + CH - 1) / CH;
    eqsc_pool<<<B * NCH, 256, 0, stream>>>(batch, sAtom, (float*)d_out, NA, B, CH);
}